// Round 3
// baseline (739.723 us; speedup 1.0000x reference)
//
#include <hip/hip_runtime.h>

// SoftCLDiceLoss fully fused, round 3:
//  - DPP wave_shl1/wave_shr1 supply neighbor columns (L.w / R.x) -> M-only
//    LDS reads (no L/R b128 redundancy)
//  - both passes use wave-aligned 32-lane strip runs (g = lane&31, 22 active)
//    with in-wave strip distance 11 rows (bank shift 8, no aliasing)
//  - erode: 8 strips x 11 rows (rows 1..86); dilate: 6 strips x 11 rows
//    (rows 11..76, masked to tile rows 12..75); wave 3 idles in dilate
//  - fixed geometry across k; garbage only ever lands in shrunk-halo cells

#define TILE 64
#define HALO 12
#define RDIM 88
#define RSTR 88
#define RAREA (RDIM * RSTR)
#define NGRP 22
#define IMG_H 1024
#define IMG_W 1024
#define NBC 16
#define NITER 11
#define LEPS 1e-6f

__device__ __forceinline__ float min3f(float a, float b, float c) { return fminf(fminf(a, b), c); }
__device__ __forceinline__ float max3f(float a, float b, float c) { return fmaxf(fmaxf(a, b), c); }
__device__ __forceinline__ float sigmoidf(float x) { return 1.0f / (1.0f + __expf(-x)); }

// lane i <- lane i-1 (DPP wave_shl1); lane 0 gets 0 (garbage-tolerated cols only)
__device__ __forceinline__ float dpp_prev(float x) {
    return __int_as_float(__builtin_amdgcn_update_dpp(0, __float_as_int(x), 0x130, 0xf, 0xf, true));
}
// lane i <- lane i+1 (DPP wave_shr1)
__device__ __forceinline__ float dpp_next(float x) {
    return __int_as_float(__builtin_amdgcn_update_dpp(0, __float_as_int(x), 0x138, 0xf, 0xf, true));
}

__global__ __launch_bounds__(256)
void skel_tile_kernel(const float* __restrict__ pred,
                      const float* __restrict__ target,
                      float* __restrict__ ws)
{
    __shared__ __align__(16) float bufA[RAREA];
    __shared__ __align__(16) float bufB[RAREA];

    const int tid = threadIdx.x;
    const int bc  = blockIdx.z & (NBC - 1);
    const int img = blockIdx.z >> 4;          // 0: skel(sigmoid(pred)), 1: skel(clip(target))
    const int r0  = blockIdx.y * TILE;
    const int c0  = blockIdx.x * TILE;

    const float* src = (img == 0) ? pred : target;
    const size_t base = (size_t)bc * (size_t)(IMG_H * IMG_W);

    // image-valid bounds in buffer coords (replicate-clamp targets)
    const int rLo = (r0 == 0) ? HALO : 0;
    const int rHi = (r0 + TILE == IMG_H) ? (TILE + HALO - 1) : (RDIM - 1);
    const int cLo = (c0 == 0) ? HALO : 0;
    const int cHi = (c0 + TILE == IMG_W) ? (TILE + HALO - 1) : (RDIM - 1);

    // ---- load 88x88 region (float4 groups, replicate-clamped at image borders) ----
    for (int idx = tid; idx < RDIM * NGRP; idx += 256) {
        int rr = idx / NGRP;
        int g  = idx - rr * NGRP;
        int gr = min(max(r0 + rr - HALO, 0), IMG_H - 1);
        int gcb = c0 + (g << 2) - HALO;
        const float* rowp = src + base + (size_t)gr * IMG_W;
        float4 v;
        if (gcb >= 0 && gcb + 4 <= IMG_W) {
            v = *(const float4*)(rowp + gcb);
        } else {
            v.x = rowp[min(max(gcb + 0, 0), IMG_W - 1)];
            v.y = rowp[min(max(gcb + 1, 0), IMG_W - 1)];
            v.z = rowp[min(max(gcb + 2, 0), IMG_W - 1)];
            v.w = rowp[min(max(gcb + 3, 0), IMG_W - 1)];
        }
        if (img == 0) {
            v.x = sigmoidf(v.x); v.y = sigmoidf(v.y);
            v.z = sigmoidf(v.z); v.w = sigmoidf(v.w);
        } else {
            v.x = fminf(fmaxf(v.x, 0.f), 1.f); v.y = fminf(fmaxf(v.y, 0.f), 1.f);
            v.z = fminf(fmaxf(v.z, 0.f), 1.f); v.w = fminf(fmaxf(v.w, 0.f), 1.f);
        }
        *(float4*)&bufA[rr * RSTR + (g << 2)] = v;
    }

    // ---- wave-aligned strip decomposition: 32-lane runs, g = lane & 31 ----
    const int sgrp = tid >> 5;                 // 32-lane group id 0..7
    const int gl   = tid & 31;                 // lane within group
    const int g22  = min(gl, NGRP - 1);        // group col (lanes 22..31 clamp to 21)
    const bool gact = (gl < NGRP);
    const int gcol = g22 << 2;

    const bool lsel = (gcol <= cLo);
    const bool rsel = (gcol + 4 > cHi);

    // erode: strip sgrp covers output rows erb..erb+10 (rows 1..88, clamp <=86)
    const int erb = 1 + sgrp * 11;

    // dilate: strips 0..5 cover rows drb..drb+10 = 11..76; sgrp>=6 idle
    const bool dact = (sgrp < 6);
    const int drb = 11 + sgrp * 11;
    const bool colv = gact && (g22 >= 3) && (g22 <= 18);

    float4 S[11];
#pragma unroll
    for (int j = 0; j < 11; ++j) S[j] = make_float4(0.f, 0.f, 0.f, 0.f);

    float* cur = bufA;   // e_k
    float* oth = bufB;

    for (int k = 0; k < NITER; ++k) {
        __syncthreads();

        // ---- erode 3x3 (min): cur -> oth, M-only reads + DPP neighbors ----
        {
            float4 h[13];
#pragma unroll
            for (int j = 0; j < 13; ++j) {
                int rr = min(max(erb - 1 + j, rLo), rHi);
                float4 M = *(const float4*)&cur[rr * RSTR + gcol];
                float lf = dpp_prev(M.w);
                float rt = dpp_next(M.x);
                lf = lsel ? M.x : lf;
                rt = rsel ? M.w : rt;
                h[j].x = min3f(lf, M.x, M.y);
                h[j].y = min3f(M.x, M.y, M.z);
                h[j].z = min3f(M.y, M.z, M.w);
                h[j].w = min3f(M.z, M.w, rt);
            }
#pragma unroll
            for (int j = 0; j < 11; ++j) {
                int r = erb + j;
                if (gact && r <= 86) {
                    float4 o;
                    o.x = min3f(h[j].x, h[j + 1].x, h[j + 2].x);
                    o.y = min3f(h[j].y, h[j + 1].y, h[j + 2].y);
                    o.z = min3f(h[j].z, h[j + 1].z, h[j + 2].z);
                    o.w = min3f(h[j].w, h[j + 1].w, h[j + 2].w);
                    *(float4*)&oth[r * RSTR + gcol] = o;
                }
            }
        }
        __syncthreads();

        // ---- dilate 3x3 (max) on oth + delta vs cur + skel update ----
        if (dact) {
            float4 hm[13];
#pragma unroll
            for (int j = 0; j < 13; ++j) {
                int rr = min(max(drb - 1 + j, rLo), rHi);
                float4 M = *(const float4*)&oth[rr * RSTR + gcol];
                float lf = dpp_prev(M.w);
                float rt = dpp_next(M.x);
                lf = lsel ? M.x : lf;
                rt = rsel ? M.w : rt;
                hm[j].x = max3f(lf, M.x, M.y);
                hm[j].y = max3f(M.x, M.y, M.z);
                hm[j].z = max3f(M.y, M.z, M.w);
                hm[j].w = max3f(M.z, M.w, rt);
            }
#pragma unroll
            for (int j = 0; j < 11; ++j) {
                int r = drb + j;
                bool valid = colv && (r >= HALO) && (r <= TILE + HALO - 1);
                float4 a = *(const float4*)&cur[r * RSTR + gcol];
                float dx = fmaxf(a.x - max3f(hm[j].x, hm[j + 1].x, hm[j + 2].x), 0.f);
                float dy = fmaxf(a.y - max3f(hm[j].y, hm[j + 1].y, hm[j + 2].y), 0.f);
                float dz = fmaxf(a.z - max3f(hm[j].z, hm[j + 1].z, hm[j + 2].z), 0.f);
                float dw = fmaxf(a.w - max3f(hm[j].w, hm[j + 1].w, hm[j + 2].w), 0.f);
                if (!valid) { dx = 0.f; dy = 0.f; dz = 0.f; dw = 0.f; }
                S[j].x += fmaxf(dx - S[j].x * dx, 0.f);
                S[j].y += fmaxf(dy - S[j].y * dy, 0.f);
                S[j].z += fmaxf(dz - S[j].z * dz, 0.f);
                S[j].w += fmaxf(dw - S[j].w * dw, 0.f);
            }
        }

        { float* t_ = cur; cur = oth; oth = t_; }
    }

    // ---- tile sums: sum(skel) and sum(skel * other) ----
    const float* osrc = (img == 0) ? target : pred;
    float s_sum = 0.0f, sp_sum = 0.0f;
    if (dact) {
#pragma unroll
        for (int j = 0; j < 11; ++j) {
            int r = drb + j;
            bool valid = colv && (r >= HALO) && (r <= TILE + HALO - 1);
            if (valid) {
                int gr = r0 + r - HALO;
                int gc = c0 + gcol - HALO;
                float4 ov = *(const float4*)&osrc[base + (size_t)gr * IMG_W + gc];
                if (img == 1) {
                    ov.x = sigmoidf(ov.x); ov.y = sigmoidf(ov.y);
                    ov.z = sigmoidf(ov.z); ov.w = sigmoidf(ov.w);
                }
                s_sum  += (S[j].x + S[j].y) + (S[j].z + S[j].w);
                sp_sum += (S[j].x * ov.x + S[j].y * ov.y) + (S[j].z * ov.z + S[j].w * ov.w);
            }
        }
    }

#pragma unroll
    for (int off = 32; off > 0; off >>= 1) {
        s_sum  += __shfl_down(s_sum,  off, 64);
        sp_sum += __shfl_down(sp_sum, off, 64);
    }
    __syncthreads();
    if ((tid & 63) == 0) {
        bufA[(tid >> 6) * 2 + 0] = sp_sum;
        bufA[(tid >> 6) * 2 + 1] = s_sum;
    }
    __syncthreads();
    if (tid == 0) {
        float a = (bufA[0] + bufA[2]) + (bufA[4] + bufA[6]);
        float b = (bufA[1] + bufA[3]) + (bufA[5] + bufA[7]);
        float* acc = ws + (size_t)blockIdx.z * 2;
        atomicAdd(acc + 0, a);   // sum skel * other
        atomicAdd(acc + 1, b);   // sum skel
    }
}

__global__ void finalize_kernel(const float* __restrict__ ws, float* __restrict__ out)
{
    if (threadIdx.x == 0) {
        float acc = 0.0f;
        for (int bc = 0; bc < NBC; ++bc) {
            float spt = ws[(0 * NBC + bc) * 2 + 0];
            float sp  = ws[(0 * NBC + bc) * 2 + 1];
            float stp = ws[(1 * NBC + bc) * 2 + 0];
            float st  = ws[(1 * NBC + bc) * 2 + 1];
            float tprec = spt / (sp + LEPS);
            float tsens = stp / (st + LEPS);
            float cl = 1.0f - 2.0f * tprec * tsens / (tprec + tsens + LEPS);
            acc += cl;
        }
        out[0] = acc / (float)NBC;
    }
}

extern "C" void kernel_launch(void* const* d_in, const int* in_sizes, int n_in,
                              void* d_out, int out_size, void* d_ws, size_t ws_size,
                              hipStream_t stream) {
    const float* pred   = (const float*)d_in[0];
    const float* target = (const float*)d_in[1];
    float* ws  = (float*)d_ws;
    float* out = (float*)d_out;

    hipMemsetAsync(d_ws, 0, 2 * NBC * 2 * sizeof(float), stream);

    dim3 grid(IMG_W / TILE, IMG_H / TILE, 2 * NBC);   // 16 x 16 x 32
    skel_tile_kernel<<<grid, 256, 0, stream>>>(pred, target, ws);
    finalize_kernel<<<1, 64, 0, stream>>>(ws, out);
}

// Round 4
// 593.817 us; speedup vs baseline: 1.2457x; 1.2457x over previous
//
#include <hip/hip_runtime.h>

// SoftCLDiceLoss fully fused, round 4: packed-f16 morphology in LDS.
// min/max are exact in f16; only input cvt + skel-update arithmetic round.
// Region 92 rows x 104 halves (SD=52 dwords), data rows 0..87, cols 0..95.
// 16 strips = 12 active lanes per 16-lane DPP row; row_shl1/row_shr1 give
// horizontal neighbors without crossing strips. Erode 6 rows/strip (1..86),
// dilate 4 rows/strip (12..75, zero idle). Interior blocks: immediate-offset
// ds_read_b128, no clamp math. 2 syncs/iter. 4 blocks/CU (38.3 KB LDS).

#define TILE 64
#define HALO 12
#define RROWS 92
#define SD 52                    // row stride in dwords
#define IMG 1024
#define NBC 16
#define NITER 11
#define LEPS 1e-6f

typedef unsigned int u32;
typedef _Float16 hv2 __attribute__((ext_vector_type(2)));

struct __align__(16) U4 { u32 v[4]; };

__device__ __forceinline__ hv2 H2(u32 x) { union { u32 u; hv2 h; } c; c.u = x; return c.h; }
__device__ __forceinline__ u32 U2(hv2 x) { union { u32 u; hv2 h; } c; c.h = x; return c.u; }
__device__ __forceinline__ hv2 hmin2v(hv2 a, hv2 b) { return __builtin_elementwise_min(a, b); }
__device__ __forceinline__ hv2 hmax2v(hv2 a, hv2 b) { return __builtin_elementwise_max(a, b); }
__device__ __forceinline__ u32 dpp_prev16(u32 x) {   // lane i <- i-1 within 16-lane row, 0-fill
    return (u32)__builtin_amdgcn_update_dpp(0, (int)x, 0x101, 0xf, 0xf, true);
}
__device__ __forceinline__ u32 dpp_next16(u32 x) {   // lane i <- i+1 within 16-lane row, 0-fill
    return (u32)__builtin_amdgcn_update_dpp(0, (int)x, 0x111, 0xf, 0xf, true);
}
__device__ __forceinline__ u32 alignh(u32 hi, u32 lo) {   // (lo.hi16, hi.lo16) packed
    return (u32)((((unsigned long long)hi << 32) | lo) >> 16);
}
__device__ __forceinline__ float sigmoidf(float x) { return 1.0f / (1.0f + __expf(-x)); }

// 3-wide horizontal min/max over 8 packed halves; neighbors via DPP.
template<bool IS_MIN>
__device__ __forceinline__ void hpass(const u32 d[4], u32 o[4]) {
    u32 dm = dpp_prev16(d[3]);
    u32 dp = dpp_next16(d[0]);
    u32 a[5];
    a[0] = alignh(d[0], dm);
    a[1] = alignh(d[1], d[0]);
    a[2] = alignh(d[2], d[1]);
    a[3] = alignh(d[3], d[2]);
    a[4] = alignh(dp,   d[3]);
#pragma unroll
    for (int q = 0; q < 4; ++q) {
        if (IS_MIN) o[q] = U2(hmin2v(hmin2v(H2(a[q]), H2(d[q])), H2(a[q + 1])));
        else        o[q] = U2(hmax2v(hmax2v(H2(a[q]), H2(d[q])), H2(a[q + 1])));
    }
}

__global__ __launch_bounds__(256, 4)
void skel_tile_kernel(const float* __restrict__ pred,
                      const float* __restrict__ target,
                      float* __restrict__ ws)
{
    __shared__ __align__(16) u32 bufA[RROWS * SD];
    __shared__ __align__(16) u32 bufB[RROWS * SD];

    const int tid = threadIdx.x;
    const int bc  = blockIdx.z & (NBC - 1);
    const int img = blockIdx.z >> 4;
    const int r0  = blockIdx.y * TILE;
    const int c0  = blockIdx.x * TILE;

    const float* src = (img == 0) ? pred : target;
    const size_t base = (size_t)bc * (size_t)(IMG * IMG);

    const bool edgeT = (blockIdx.y == 0);
    const bool edgeB = (blockIdx.y == 15);
    const bool edgeL = (blockIdx.x == 0);
    const bool edgeR = (blockIdx.x == 15);
    const int rdLo = edgeT ? 12 : 0;
    const int rdHi = edgeB ? 75 : (RROWS - 1);

    // ---- load region rows 0..87, cols 0..95 (halves), replicate-clamped ----
    for (int t = tid; t < 88 * 12; t += 256) {
        int rr = t / 12;
        int g  = t - rr * 12;
        int gr = min(max(r0 + rr - HALO, 0), IMG - 1);
        const float* rowp = src + base + (size_t)gr * IMG;
        float f[8];
        int gc0 = c0 + 8 * g - HALO;
        if (g <= 10 && gc0 >= 0 && gc0 + 8 <= IMG) {
            float4 v0 = *(const float4*)(rowp + gc0);
            float4 v1 = *(const float4*)(rowp + gc0 + 4);
            f[0] = v0.x; f[1] = v0.y; f[2] = v0.z; f[3] = v0.w;
            f[4] = v1.x; f[5] = v1.y; f[6] = v1.z; f[7] = v1.w;
        } else {
#pragma unroll
            for (int i = 0; i < 8; ++i) {
                int rc = min(8 * g + i, 87);                    // region col clamp (pad cols)
                int gc = min(max(c0 + rc - HALO, 0), IMG - 1);  // image col clamp
                f[i] = rowp[gc];
            }
        }
        U4 u;
#pragma unroll
        for (int q = 0; q < 4; ++q) {
            float a = f[2 * q], b = f[2 * q + 1];
            if (img == 0) { a = sigmoidf(a); b = sigmoidf(b); }
            else { a = fminf(fmaxf(a, 0.f), 1.f); b = fminf(fmaxf(b, 0.f), 1.f); }
            hv2 p; p[0] = (_Float16)a; p[1] = (_Float16)b;
            u.v[q] = U2(p);
        }
        *(uint4*)&bufA[rr * SD + 4 * g] = *(const uint4*)u.v;
    }

    // ---- strip / lane geometry ----
    const int strip = tid >> 4;                 // 0..15 (strip % 4 == DPP row)
    const int g16   = tid & 15;                 // lane within DPP row
    const int coldw = 4 * min(g16, 11);         // clamped dword col (16B aligned)
    const bool wact = (g16 < 12);

    const int rs_e = min(1 + 6 * strip, 85);    // erode out rows rs_e..rs_e+5 (mask <=86)
    const int rs_d = 12 + 4 * strip;            // dilate out rows rs_d..rs_d+3 (12..75 exact)

    // per-half column-validity masks (region cols 12..75)
    u32 mk[4];
#pragma unroll
    for (int q = 0; q < 4; ++q) {
        int c = 8 * g16 + 2 * q;
        mk[q] = ((c >= 12 && c <= 75) ? 0xFFFFu : 0u) |
                ((c + 1 >= 12 && c + 1 <= 75) ? 0xFFFF0000u : 0u);
    }

    hv2 Sv[4][4];
#pragma unroll
    for (int j = 0; j < 4; ++j)
#pragma unroll
        for (int q = 0; q < 4; ++q) { Sv[j][q][0] = (_Float16)0; Sv[j][q][1] = (_Float16)0; }

    u32* cur = bufA;
    u32* oth = bufB;

    __syncthreads();

    for (int k = 0; k < NITER; ++k) {
        // ---- erode 3x3 (min): cur -> oth; no row clamps ever ----
        {
            U4 h[8];
            const u32* p = cur + (rs_e - 1) * SD + coldw;
#pragma unroll
            for (int j = 0; j < 8; ++j) {
                U4 u; *(uint4*)u.v = *(const uint4*)(p + j * SD);
                hpass<true>(u.v, h[j].v);
            }
            u32* q = oth + rs_e * SD + coldw;
#pragma unroll
            for (int j = 0; j < 6; ++j) {
                int row = rs_e + j;
                if (wact && row <= 86) {
                    U4 o;
#pragma unroll
                    for (int qd = 0; qd < 4; ++qd)
                        o.v[qd] = U2(hmin2v(hmin2v(H2(h[j].v[qd]), H2(h[j + 1].v[qd])),
                                            H2(h[j + 2].v[qd])));
                    *(uint4*)(q + j * SD) = *(const uint4*)o.v;
                }
            }
        }
        __syncthreads();

        // ---- dilate 3x3 (max) on oth + delta vs cur + skel update ----
        {
            U4 w[6], m[6];
            if (!(edgeT || edgeB)) {
                const u32* p = oth + (rs_d - 1) * SD + coldw;
#pragma unroll
                for (int j = 0; j < 6; ++j)
                    *(uint4*)w[j].v = *(const uint4*)(p + j * SD);
            } else {
#pragma unroll
                for (int j = 0; j < 6; ++j) {
                    int rr = min(max(rs_d - 1 + j, rdLo), rdHi);
                    *(uint4*)w[j].v = *(const uint4*)(oth + rr * SD + coldw);
                }
            }
#pragma unroll
            for (int j = 0; j < 6; ++j) hpass<false>(w[j].v, m[j].v);

            // image-edge column repair (replicate): 2/16 blocks, output patch
            if (edgeL && g16 == 1) {
#pragma unroll
                for (int j = 0; j < 6; ++j) {   // out col12 lo := max(x12,x13)
                    u32 d2 = w[j].v[2];
                    u32 sw = (d2 >> 16) | (d2 << 16);
                    u32 pm = U2(hmax2v(H2(d2), H2(sw)));
                    m[j].v[2] = (m[j].v[2] & 0xFFFF0000u) | (pm & 0xFFFFu);
                }
            }
            if (edgeR && g16 == 9) {
#pragma unroll
                for (int j = 0; j < 6; ++j) {   // out col75 hi := max(x74,x75)
                    u32 d1 = w[j].v[1];
                    u32 sw = (d1 >> 16) | (d1 << 16);
                    u32 pm = U2(hmax2v(H2(d1), H2(sw)));
                    m[j].v[1] = (m[j].v[1] & 0x0000FFFFu) | (pm & 0xFFFF0000u);
                }
            }

            const u32* pc = cur + rs_d * SD + coldw;
#pragma unroll
            for (int j = 0; j < 4; ++j) {
                U4 a; *(uint4*)a.v = *(const uint4*)(pc + j * SD);
#pragma unroll
                for (int qd = 0; qd < 4; ++qd) {
                    hv2 D = hmax2v(hmax2v(H2(m[j].v[qd]), H2(m[j + 1].v[qd])),
                                   H2(m[j + 2].v[qd]));
                    hv2 z; z[0] = (_Float16)0; z[1] = (_Float16)0;
                    hv2 d = hmax2v(H2(a.v[qd]) - D, z);
                    d = H2(U2(d) & mk[qd]);            // mask invalid halves (NaN-safe)
                    hv2 s = Sv[j][qd];
                    hv2 t = hmax2v(d - s * d, z);
                    Sv[j][qd] = s + t;
                }
            }
        }

        { u32* t_ = cur; cur = oth; oth = t_; }
        __syncthreads();
    }

    // ---- tile sums: sum(skel), sum(skel * other) ----
    const float* osrc = (img == 0) ? target : pred;
    float s_sum = 0.0f, sp_sum = 0.0f;
#pragma unroll
    for (int j = 0; j < 4; ++j) {
        int orow = r0 + 4 * strip + j;
#pragma unroll
        for (int q = 0; q < 4; ++q) {
#pragma unroll
            for (int e = 0; e < 2; ++e) {
                int rc = 8 * g16 + 2 * q + e;
                if (rc >= 12 && rc <= 75) {
                    float sv = (float)Sv[j][q][e];
                    float ov = osrc[base + (size_t)orow * IMG + (c0 + rc - HALO)];
                    if (img == 1) ov = sigmoidf(ov);
                    s_sum  += sv;
                    sp_sum += sv * ov;
                }
            }
        }
    }

#pragma unroll
    for (int off = 32; off > 0; off >>= 1) {
        s_sum  += __shfl_down(s_sum,  off, 64);
        sp_sum += __shfl_down(sp_sum, off, 64);
    }
    float* red = (float*)bufA;
    if ((tid & 63) == 0) {
        red[(tid >> 6) * 2 + 0] = sp_sum;
        red[(tid >> 6) * 2 + 1] = s_sum;
    }
    __syncthreads();
    if (tid == 0) {
        float a = (red[0] + red[2]) + (red[4] + red[6]);
        float b = (red[1] + red[3]) + (red[5] + red[7]);
        float* acc = ws + (size_t)blockIdx.z * 2;
        atomicAdd(acc + 0, a);   // sum skel * other
        atomicAdd(acc + 1, b);   // sum skel
    }
}

__global__ void finalize_kernel(const float* __restrict__ ws, float* __restrict__ out)
{
    if (threadIdx.x == 0) {
        float acc = 0.0f;
        for (int bc = 0; bc < NBC; ++bc) {
            float spt = ws[(0 * NBC + bc) * 2 + 0];
            float sp  = ws[(0 * NBC + bc) * 2 + 1];
            float stp = ws[(1 * NBC + bc) * 2 + 0];
            float st  = ws[(1 * NBC + bc) * 2 + 1];
            float tprec = spt / (sp + LEPS);
            float tsens = stp / (st + LEPS);
            acc += 1.0f - 2.0f * tprec * tsens / (tprec + tsens + LEPS);
        }
        out[0] = acc / (float)NBC;
    }
}

extern "C" void kernel_launch(void* const* d_in, const int* in_sizes, int n_in,
                              void* d_out, int out_size, void* d_ws, size_t ws_size,
                              hipStream_t stream) {
    const float* pred   = (const float*)d_in[0];
    const float* target = (const float*)d_in[1];
    float* ws  = (float*)d_ws;
    float* out = (float*)d_out;

    hipMemsetAsync(d_ws, 0, 2 * NBC * 2 * sizeof(float), stream);

    dim3 grid(IMG / TILE, IMG / TILE, 2 * NBC);   // 16 x 16 x 32
    skel_tile_kernel<<<grid, 256, 0, stream>>>(pred, target, ws);
    finalize_kernel<<<1, 64, 0, stream>>>(ws, out);
}